// Round 2
// baseline (387.920 us; speedup 1.0000x reference)
//
#include <hip/hip_runtime.h>

#define D 512
#define D4 (D / 4)
#define MAXC 256
#define FEPS 1e-12f
#define FBIG 3.0e38f
#define DROWS 8
#define TJ 16     // j-rows per LDS tile in k_pos
#define RPB 16    // i-rows per block in k_pos (8 waves x 2 rows)

__device__ __forceinline__ float wave_rsum(float v) {
#pragma unroll
    for (int o = 32; o > 0; o >>= 1) v += __shfl_down(v, o);
    return v;
}

__device__ __forceinline__ float wave_rsum_all(float v) {
#pragma unroll
    for (int o = 32; o > 0; o >>= 1) v += __shfl_xor(v, o);
    return v;
}

__device__ __forceinline__ float dot4(const float4 a, const float4 b) {
    return a.x * b.x + a.y * b.y + a.z * b.z + a.w * b.w;
}

// --- 1. row L2-normalize + a2[i] + fused class histogram ---
__global__ void k_normalize(const float* __restrict__ emb, const int* __restrict__ targets,
                            float* __restrict__ embn, float* __restrict__ a2,
                            int* __restrict__ ccount) {
    const int i = blockIdx.x;
    const int tid = threadIdx.x;  // 128 threads, float4 each
    __shared__ float red[2];
    const float4 x = ((const float4*)(emb + (size_t)i * D))[tid];
    float ss = x.x * x.x + x.y * x.y + x.z * x.z + x.w * x.w;
    ss = wave_rsum(ss);
    if ((tid & 63) == 0) red[tid >> 6] = ss;
    __syncthreads();
    const float tot = red[0] + red[1];
    const float inv = 1.0f / fmaxf(sqrtf(tot), FEPS);
    const float4 y = make_float4(x.x * inv, x.y * inv, x.z * inv, x.w * inv);
    ((float4*)(embn + (size_t)i * D))[tid] = y;
    float s2 = y.x * y.x + y.y * y.y + y.z * y.z + y.w * y.w;
    s2 = wave_rsum(s2);
    __syncthreads();
    if ((tid & 63) == 0) red[tid >> 6] = s2;
    __syncthreads();
    if (tid == 0) {
        a2[i] = red[0] + red[1];
        atomicAdd(&ccount[targets[i]], 1);
    }
}

// --- 2a. exclusive prefix over classes ---
__global__ void k_scan(const int* __restrict__ ccount, int* __restrict__ coff,
                       const int* __restrict__ ncls) {
    __shared__ int lc[MAXC];
    const int C = *ncls;
    for (int c = threadIdx.x; c < C; c += blockDim.x) lc[c] = ccount[c];
    __syncthreads();
    if (threadIdx.x == 0) {
        int s = 0;
        for (int c = 0; c < C; ++c) { coff[c] = s; s += lc[c]; }
        coff[C] = s;
    }
}

// --- 2b. deterministic (index-ordered) per-class row lists ---
__global__ void k_build(const int* __restrict__ t, const int* __restrict__ coff,
                        int* __restrict__ clist, int n, const int* __restrict__ ncls) {
    const int C = *ncls;
    __shared__ int wtot[4];
    for (int c = blockIdx.x; c < C; c += gridDim.x) {
        int base = coff[c];
        for (int start = 0; start < n; start += 256) {
            const int j = start + (int)threadIdx.x;
            const bool flag = (j < n) && (t[j] == c);
            const unsigned long long m = __ballot(flag);
            const int lane = threadIdx.x & 63;
            const int w = threadIdx.x >> 6;
            const int pre = __popcll(m & ((1ull << lane) - 1ull));
            if (lane == 0) wtot[w] = __popcll(m);
            __syncthreads();
            int woff = 0;
            for (int k = 0; k < w; ++k) woff += wtot[k];
            const int tot = wtot[0] + wtot[1] + wtot[2] + wtot[3];
            if (flag) clist[base + woff + pre] = j;
            base += tot;
            __syncthreads();
        }
    }
}

// --- 3. class centers (coalesced float4) + cc2[c] ---
__global__ void k_centers(const float* __restrict__ embn, const int* __restrict__ clist,
                          const int* __restrict__ coff, const int* __restrict__ ccount,
                          float* __restrict__ centers, float* __restrict__ cc2) {
    const int c = blockIdx.x;   // grid = MAXC
    const int tid = threadIdx.x;  // 128 = D4
    const int cnt = ccount[c];
    const int off = (cnt > 0) ? coff[c] : 0;
    float4 s = make_float4(0.f, 0.f, 0.f, 0.f);
    for (int m = 0; m < cnt; ++m) {
        const int j = clist[off + m];
        const float4 e = ((const float4*)(embn + (size_t)j * D))[tid];
        s.x += e.x; s.y += e.y; s.z += e.z; s.w += e.w;
    }
    const float inv = 1.0f / fmaxf((float)cnt, 1e-6f);
    const float4 v = make_float4(s.x * inv, s.y * inv, s.z * inv, s.w * inv);
    ((float4*)(centers + (size_t)c * D))[tid] = v;
    float ss = dot4(v, v);
    ss = wave_rsum(ss);
    __shared__ float red[2];
    if ((tid & 63) == 0) red[tid >> 6] = ss;
    __syncthreads();
    if (tid == 0) cc2[c] = red[0] + red[1];
}

// --- 4. d_neg_min: 8 rows per block, one thread per class ---
__global__ void k_dneg(const float* __restrict__ embn, const float* __restrict__ a2,
                       const int* __restrict__ t, const float* __restrict__ centers,
                       const float* __restrict__ cc2, float* __restrict__ dneg,
                       int n, const int* __restrict__ ncls) {
    const int C = *ncls;
    const int i0 = blockIdx.x * DROWS;
    __shared__ __align__(16) float lrow[DROWS][D];
    __shared__ float la2[DROWS];
    __shared__ int lt[DROWS];
    __shared__ float mins[DROWS][128];
#pragma unroll
    for (int r = 0; r < DROWS; ++r) {
        if (i0 + r < n)
            ((float4*)lrow[r])[threadIdx.x] =
                ((const float4*)(embn + (size_t)(i0 + r) * D))[threadIdx.x];
    }
    if (threadIdx.x < DROWS) {
        const int ii = i0 + (int)threadIdx.x;
        la2[threadIdx.x] = (ii < n) ? a2[ii] : 0.f;
        lt[threadIdx.x] = (ii < n) ? t[ii] : -1;
    }
    __syncthreads();
    const int c = threadIdx.x;
    float best[DROWS];
    if (c < C) {
        float acc[DROWS];
#pragma unroll
        for (int r = 0; r < DROWS; ++r) acc[r] = 0.f;
        const float4* cp = (const float4*)(centers + (size_t)c * D);
        for (int k = 0; k < D4; ++k) {
            const float4 cv = cp[k];
#pragma unroll
            for (int r = 0; r < DROWS; ++r) {
                const float4 ev = ((const float4*)lrow[r])[k];
                acc[r] += cv.x * ev.x + cv.y * ev.y + cv.z * ev.z + cv.w * ev.w;
            }
        }
        const float c2 = cc2[c];
#pragma unroll
        for (int r = 0; r < DROWS; ++r) {
            const float sq = la2[r] + c2 - 2.f * acc[r];
            float dv = sqrtf(fmaxf(sq, FEPS));
            if (lt[r] == c) dv = FBIG;
            best[r] = dv;
        }
    } else {
#pragma unroll
        for (int r = 0; r < DROWS; ++r) best[r] = FBIG;
    }
#pragma unroll
    for (int r = 0; r < DROWS; ++r) mins[r][threadIdx.x] = best[r];
    __syncthreads();
    for (int s = 64; s > 0; s >>= 1) {
        if (threadIdx.x < s) {
#pragma unroll
            for (int r = 0; r < DROWS; ++r)
                mins[r][threadIdx.x] = fminf(mins[r][threadIdx.x], mins[r][threadIdx.x + s]);
        }
        __syncthreads();
    }
    if (threadIdx.x < DROWS && i0 + (int)threadIdx.x < n)
        dneg[i0 + threadIdx.x] = mins[threadIdx.x][0];
}

// --- 5. class-tiled hardest-positive mining + d_pos ---
// block = (i-tile of 16 class rows, class); 512 threads = 8 waves x 2 rows each.
// j-rows staged once per block through a 16-row LDS tile (shared by all waves).
__global__ __launch_bounds__(512) void k_pos(
    const float* __restrict__ embn, const float* __restrict__ a2,
    const int* __restrict__ clist, const int* __restrict__ coff,
    const int* __restrict__ ccount, float* __restrict__ dpos,
    float* __restrict__ dvalid) {
    const int c = blockIdx.y;
    const int m = ccount[c];
    const int tile0 = blockIdx.x * RPB;
    if (tile0 >= m) return;  // uniform exit
    const int off = coff[c];
    const int tid = threadIdx.x;
    const int lane = tid & 63;
    const int w = tid >> 6;  // wave 0..7

    __shared__ __align__(16) float Bt[TJ][D];  // 32 KB
    __shared__ float a2s[TJ];
    __shared__ int jgs[TJ];

    for (int base = tile0; base < m; base += 16 * RPB) {
        const int sA = base + 2 * w;
        const int sB = sA + 1;
        const bool hA = sA < m;
        const bool hB = sB < m;
        const int iA = hA ? clist[off + sA] : 0;
        const int iB = hB ? clist[off + sB] : 0;
        float4 a0A, a1A, a0B, a1B;
        float a2A = 0.f, a2B = 0.f;
        if (hA) {
            const float4* ap = (const float4*)(embn + (size_t)iA * D);
            a0A = ap[lane]; a1A = ap[lane + 64]; a2A = a2[iA];
        }
        if (hB) {
            const float4* bp = (const float4*)(embn + (size_t)iB * D);
            a0B = bp[lane]; a1B = bp[lane + 64]; a2B = a2[iB];
        }
        float tA0 = -FBIG, tA1 = -FBIG, tA2 = -FBIG;
        float tB0 = -FBIG, tB1 = -FBIG, tB2 = -FBIG;
        int jA0 = -1, jA1 = -1, jA2 = -1;
        int jB0 = -1, jB1 = -1, jB2 = -1;

        for (int jt = 0; jt < m; jt += TJ) {
            const int rows = min(TJ, m - jt);
            __syncthreads();  // protect previous tile
            for (int u = tid; u < rows * D4; u += 512) {
                const int r = u >> 7;
                const int k4 = u & (D4 - 1);
                const int jg = clist[off + jt + r];
                ((float4*)Bt[r])[k4] = ((const float4*)(embn + (size_t)jg * D))[k4];
            }
            if (tid < rows) {
                const int jg = clist[off + jt + tid];
                jgs[tid] = jg;
                a2s[tid] = a2[jg];
            }
            __syncthreads();
            if (hA) {
                for (int jj = 0; jj < rows; ++jj) {
                    const float4 b0 = ((const float4*)Bt[jj])[lane];
                    const float4 b1 = ((const float4*)Bt[jj])[lane + 64];
                    float pA = dot4(a0A, b0) + dot4(a1A, b1);
                    float pB = hB ? (dot4(a0B, b0) + dot4(a1B, b1)) : 0.f;
#pragma unroll
                    for (int o = 32; o > 0; o >>= 1) {
                        pA += __shfl_xor(pA, o);
                        pB += __shfl_xor(pB, o);
                    }
                    const int jg = jgs[jj];
                    const float b2 = a2s[jj];
                    if (jg != iA) {
                        const float sq = a2A + b2 - 2.f * pA;
                        if (sq > tA0)      { tA2=tA1; jA2=jA1; tA1=tA0; jA1=jA0; tA0=sq; jA0=jg; }
                        else if (sq > tA1) { tA2=tA1; jA2=jA1; tA1=sq; jA1=jg; }
                        else if (sq > tA2) { tA2=sq; jA2=jg; }
                    }
                    if (hB && jg != iB) {
                        const float sq = a2B + b2 - 2.f * pB;
                        if (sq > tB0)      { tB2=tB1; jB2=jB1; tB1=tB0; jB1=jB0; tB0=sq; jB0=jg; }
                        else if (sq > tB1) { tB2=tB1; jB2=jB1; tB1=sq; jB1=jg; }
                        else if (sq > tB2) { tB2=sq; jB2=jg; }
                    }
                }
            }
        }

        // d_pos for the two rows this wave owns
        if (hA) {
            const int nw = (jA0 >= 0) + (jA1 >= 0) + (jA2 >= 0);
            if (nw > 0) {
                const int w0 = jA0;
                const int w1 = (jA1 >= 0) ? jA1 : w0;
                const int w2 = (jA2 >= 0) ? jA2 : w1;
                const float4* r0 = (const float4*)(embn + (size_t)w0 * D);
                const float4* r1 = (const float4*)(embn + (size_t)w1 * D);
                const float4* r2 = (const float4*)(embn + (size_t)w2 * D);
                float acc = 0.f;
#pragma unroll
                for (int s = 0; s < 2; ++s) {
                    const int k4 = lane + 64 * s;
                    const float4 v0 = r0[k4], v1 = r1[k4], v2 = r2[k4];
                    const float4 a = (s == 0) ? a0A : a1A;
                    const float cx = (v0.x + v1.x + v2.x) * (1.f / 3.f);
                    const float cy = (v0.y + v1.y + v2.y) * (1.f / 3.f);
                    const float cz = (v0.z + v1.z + v2.z) * (1.f / 3.f);
                    const float cw = (v0.w + v1.w + v2.w) * (1.f / 3.f);
                    const float dx = a.x - cx, dy = a.y - cy, dz = a.z - cz, dw = a.w - cw;
                    acc += dx * dx + dy * dy + dz * dz + dw * dw;
                }
                acc = wave_rsum_all(acc);
                if (lane == 0) { dpos[iA] = sqrtf(fmaxf(acc, FEPS)); dvalid[iA] = 1.f; }
            } else if (lane == 0) { dpos[iA] = 0.f; dvalid[iA] = 0.f; }
        }
        if (hB) {
            const int nw = (jB0 >= 0) + (jB1 >= 0) + (jB2 >= 0);
            if (nw > 0) {
                const int w0 = jB0;
                const int w1 = (jB1 >= 0) ? jB1 : w0;
                const int w2 = (jB2 >= 0) ? jB2 : w1;
                const float4* r0 = (const float4*)(embn + (size_t)w0 * D);
                const float4* r1 = (const float4*)(embn + (size_t)w1 * D);
                const float4* r2 = (const float4*)(embn + (size_t)w2 * D);
                float acc = 0.f;
#pragma unroll
                for (int s = 0; s < 2; ++s) {
                    const int k4 = lane + 64 * s;
                    const float4 v0 = r0[k4], v1 = r1[k4], v2 = r2[k4];
                    const float4 a = (s == 0) ? a0B : a1B;
                    const float cx = (v0.x + v1.x + v2.x) * (1.f / 3.f);
                    const float cy = (v0.y + v1.y + v2.y) * (1.f / 3.f);
                    const float cz = (v0.z + v1.z + v2.z) * (1.f / 3.f);
                    const float cw = (v0.w + v1.w + v2.w) * (1.f / 3.f);
                    const float dx = a.x - cx, dy = a.y - cy, dz = a.z - cz, dw = a.w - cw;
                    acc += dx * dx + dy * dy + dz * dz + dw * dw;
                }
                acc = wave_rsum_all(acc);
                if (lane == 0) { dpos[iB] = sqrtf(fmaxf(acc, FEPS)); dvalid[iB] = 1.f; }
            } else if (lane == 0) { dpos[iB] = 0.f; dvalid[iB] = 0.f; }
        }
    }
}

// --- 6. stable softplus + masked mean ---
__global__ void k_loss(const float* __restrict__ dpos, const float* __restrict__ dneg,
                       const float* __restrict__ dvalid, float* __restrict__ accum, int n) {
    const int i = blockIdx.x * blockDim.x + threadIdx.x;
    float l = 0.f, v = 0.f;
    if (i < n) {
        v = dvalid[i];
        const float x = dpos[i] - dneg[i];
        const float sp = fmaxf(x, 0.f) + log1pf(expf(-fabsf(x)));
        l = sp * v;
    }
    l = wave_rsum(l);
    v = wave_rsum(v);
    __shared__ float wl[4], wv[4];
    const int lane = threadIdx.x & 63, w = threadIdx.x >> 6;
    if (lane == 0) { wl[w] = l; wv[w] = v; }
    __syncthreads();
    if (threadIdx.x == 0) {
        atomicAdd(&accum[0], wl[0] + wl[1] + wl[2] + wl[3]);
        atomicAdd(&accum[1], wv[0] + wv[1] + wv[2] + wv[3]);
    }
}

__global__ void k_final(const float* __restrict__ accum, float* __restrict__ out) {
    out[0] = accum[0] / fmaxf(accum[1], 1.0f);
}

extern "C" void kernel_launch(void* const* d_in, const int* in_sizes, int n_in,
                              void* d_out, int out_size, void* d_ws, size_t ws_size,
                              hipStream_t stream) {
    const float* emb = (const float*)d_in[0];
    const int* targets = (const int*)d_in[1];
    const int* ncls = (const int*)d_in[2];
    const int n = in_sizes[1];  // 8192

    float* fp = (float*)d_ws;
    float* embn = fp;    fp += (size_t)n * D;
    float* a2 = fp;      fp += n;
    float* centers = fp; fp += (size_t)MAXC * D;
    float* cc2 = fp;     fp += MAXC;
    float* dneg = fp;    fp += n;
    float* dpos = fp;    fp += n;
    float* dvalid = fp;  fp += n;
    float* accum = fp;   fp += 2;
    int* ccount = (int*)fp; fp += MAXC;
    int* coff = (int*)fp;   fp += MAXC + 1;
    int* clist = (int*)fp;  fp += n;

    hipMemsetAsync(ccount, 0, MAXC * sizeof(int), stream);
    hipMemsetAsync(accum, 0, 2 * sizeof(float), stream);

    k_normalize<<<n, 128, 0, stream>>>(emb, targets, embn, a2, ccount);
    k_scan<<<1, 256, 0, stream>>>(ccount, coff, ncls);
    k_build<<<128, 256, 0, stream>>>(targets, coff, clist, n, ncls);
    k_centers<<<MAXC, 128, 0, stream>>>(embn, clist, coff, ccount, centers, cc2);
    k_dneg<<<(n + DROWS - 1) / DROWS, 128, 0, stream>>>(embn, a2, targets, centers, cc2, dneg, n, ncls);
    k_pos<<<dim3(16, MAXC), 512, 0, stream>>>(embn, a2, clist, coff, ccount, dpos, dvalid);
    k_loss<<<(n + 255) / 256, 256, 0, stream>>>(dpos, dneg, dvalid, accum, n);
    k_final<<<1, 1, 0, stream>>>(accum, (float*)d_out);
}